// Round 3
// baseline (2600.951 us; speedup 1.0000x reference)
//
#include <hip/hip_runtime.h>
#include <hip/hip_bf16.h>

namespace {

constexpr int C = 128, N = 256, T = 64, Bsz = 8;
constexpr int TILE = T * C;                       // 8192 elements per (b,n) slab
constexpr size_t BIGE = (size_t)Bsz * N * T * C;  // 16,777,216 elements

__device__ __forceinline__ float bfu(unsigned short u) {
  unsigned int x = ((unsigned int)u) << 16;
  return __uint_as_float(x);
}
// flag-aware load: f32 != 0 -> input is fp32, else bf16
__device__ __forceinline__ float ld(const void* p, size_t i, int f32) {
  if (f32) return ((const float*)p)[i];
  return bfu(((const unsigned short*)p)[i]);
}
__device__ __forceinline__ float sigm(float x) { return 1.f / (1.f + __expf(-x)); }

// ---------------------------------------------------------------- dtype sniffer
__global__ __launch_bounds__(64) void k_sniff(const unsigned short* x, int* flag) {
  __shared__ int cnt[64];
  int tid = threadIdx.x;
  int c = 0;
  for (int u = 0; u < 8; ++u) {
    unsigned short v = x[tid * 8 + u];
    int e = (v >> 7) & 255;
    c += (e >= 97 && e <= 157) ? 1 : 0;
  }
  cnt[tid] = c;
  __syncthreads();
  if (tid == 0) {
    int s = 0;
    for (int i = 0; i < 64; ++i) s += cnt[i];
    flag[0] = (s < 435) ? 1 : 0;  // <85% plausible-bf16 words -> fp32 input
  }
}

// ---------------------------------------------------------------- x -> fp32 copy
__global__ __launch_bounds__(256) void k_cvtx(const void* x, const int* flag, float* xf) {
  int f = flag[0];
  size_t i0 = ((size_t)blockIdx.x * 256 + threadIdx.x) * 4;
  size_t stride = (size_t)gridDim.x * 1024;
  if (f) {
    const float4* src = (const float4*)x;
    for (size_t i = i0; i < BIGE; i += stride) *(float4*)&xf[i] = src[i >> 2];
  } else {
    const ushort4* src = (const ushort4*)x;
    for (size_t i = i0; i < BIGE; i += stride) {
      ushort4 u = src[i >> 2];
      float4 v; v.x = bfu(u.x); v.y = bfu(u.y); v.z = bfu(u.z); v.w = bfu(u.w);
      *(float4*)&xf[i] = v;
    }
  }
}

// ---------------------------------------------------------------- prep (weights -> fp32, k-major)
struct PrepArgs {
  const int* flag;
  const void *wq, *wk, *w1, *w2, *th, *dxc, *dec, *dc1;
  const void *bq, *bk, *b1, *b2, *l0g, *l0b, *l1g, *l1b, *dxcb, *decb, *dc1b, *dp2w, *dp2b;
  float *wqkT, *w1T, *w2T, *thT, *dxcT, *decT, *dc1T;
  float *bqk, *b1f, *b2f, *l0gf, *l0bf, *l1gf, *l1bf, *dxcbf, *decbf, *dc1bf, *dp2wf, *dp2bf;
};

__global__ __launch_bounds__(256) void k_prep(PrepArgs a) {
  int f = a.flag[0];
  int idx = blockIdx.x * blockDim.x + threadIdx.x;
  int stride = gridDim.x * blockDim.x;
  // wqkT[k][o], k = j*128+i, o<128 -> wq else wk. src w[o,i,0,j] = w[(o*128+i)*3 + j]
  for (int i = idx; i < 384 * 256; i += stride) {
    int k = i >> 8, o = i & 255, j = k >> 7, ii = k & 127;
    a.wqkT[i] = (o < 128) ? ld(a.wq, (o * 128 + ii) * 3 + j, f)
                          : ld(a.wk, ((o - 128) * 128 + ii) * 3 + j, f);
  }
  for (int i = idx; i < 16384; i += stride) {
    int k = i >> 7, o = i & 127;
    a.w1T[i] = ld(a.w1, o * 128 + k, f);
    a.w2T[i] = ld(a.w2, o * 128 + k, f);
    a.thT[i] = ld(a.th, o * 128 + k, f);
  }
  for (int i = idx; i < 384 * 128; i += stride) {
    int k = i >> 7, o = i & 127, j = k >> 7, ii = k & 127;
    int s = (o * 128 + ii) * 3 + j;
    a.dxcT[i] = ld(a.dxc, s, f); a.decT[i] = ld(a.dec, s, f); a.dc1T[i] = ld(a.dc1, s, f);
  }
  for (int i = idx; i < 256; i += stride) {
    a.bqk[i] = (i < 128) ? ld(a.bq, i, f) : ld(a.bk, i - 128, f);
    a.dp2wf[i] = ld(a.dp2w, i, f);
  }
  for (int i = idx; i < 128; i += stride) {
    a.b1f[i] = ld(a.b1, i, f);   a.b2f[i] = ld(a.b2, i, f);
    a.l0gf[i] = ld(a.l0g, i, f); a.l0bf[i] = ld(a.l0b, i, f);
    a.l1gf[i] = ld(a.l1g, i, f); a.l1bf[i] = ld(a.l1b, i, f);
    a.dxcbf[i] = ld(a.dxcb, i, f); a.decbf[i] = ld(a.decb, i, f); a.dc1bf[i] = ld(a.dc1b, i, f);
  }
  if (idx < 2) a.dp2bf[idx] = ld(a.dp2b, idx, f);
}

__global__ __launch_bounds__(256) void k_lap(const void* adj, const int* flag, float* lap) {
  __shared__ float dsh[256];
  int f = flag[0];
  int tid = threadIdx.x;
  float s = 0.f;
  for (int m = 0; m < 256; ++m) s += ld(adj, tid * 256 + m, f);
  dsh[tid] = 1.f / sqrtf(s);
  __syncthreads();
  for (int idx = tid; idx < 65536; idx += 256) {
    int n = idx >> 8, m = idx & 255;
    lap[idx] = ld(adj, idx, f) * dsh[n] * dsh[m];
  }
}

__global__ __launch_bounds__(128) void k_emb(const int* step, const int* flag,
                                             const void* p1w, const void* p1b,
                                             const void* p2w, const void* p2b, float* e) {
  int b = blockIdx.x, c = threadIdx.x;
  int f = flag[0];
  __shared__ float tab[128], e1[128];
  float sv = (float)step[b];
  int i0 = c & 63;
  float fr = powf(10.f, (float)i0 / 63.f * 4.f);
  float ang = sv * fr;
  tab[c] = (c < 64) ? sinf(ang) : cosf(ang);
  __syncthreads();
  float a = ld(p1b, c, f);
  for (int i = 0; i < 128; ++i) a += tab[i] * ld(p1w, c * 128 + i, f);
  a = a * sigm(a);
  e1[c] = a;
  __syncthreads();
  float a2 = ld(p2b, c, f);
  for (int i = 0; i < 128; ++i) a2 += e1[i] * ld(p2w, c * 128 + i, f);
  e[b * 128 + c] = a2 * sigm(a2);
}

// ================================================================ mega1:
// per (b,n): xf -> QK conv GEMM, V GEMM, 8-head temporal attention, o.w2^T,
// LN0 + residual(x) -> xp (fp32) to g0.  All intermediates in LDS.
__global__ __launch_bounds__(256, 1) void k_mega1(
    const float* xf, const float* wqkT, const float* bqk,
    const float* w1T, const float* b1f, const float* w2T, const float* b2f,
    const float* l0g, const float* l0b, float* g0) {
  int bn = blockIdx.x, b = bn >> 8, n = bn & 255;
  __shared__ float xs[128 * 68];    // x tile, [c][t+1], zero pads at tt=0,65
  __shared__ float qls[64 * 132];   // q [t][c]; later o [t][c]
  __shared__ float kls[64 * 132];   // k [t][c]; later ls = o.w2^T [t][c]
  __shared__ float vls[64 * 132];   // v [t][c]; later o^T [c*66+t]
  __shared__ float ss[64 * 68];     // per-head scores [t][s]
  __shared__ float red[256], red2[256];
  __shared__ float mxr[64], invr[64], mrow[64], vrow[64];
  int tid = threadIdx.x;
  const float* xb = xf + (size_t)b * C * N * T + (size_t)n * T;
  for (int idx = tid * 4; idx < TILE; idx += 1024) {
    int i = idx >> 6, t = idx & 63;   // t multiple of 4
    float4 v4 = *(const float4*)&xb[(size_t)i * N * T + t];
    float* row = &xs[i * 68 + t + 1];
    row[0] = v4.x; row[1] = v4.y; row[2] = v4.z; row[3] = v4.w;
  }
  if (tid < 128) { xs[tid * 68] = 0.f; xs[tid * 68 + 65] = 0.f; }
  __syncthreads();
  // ---- QK conv GEMM (K = 3*128, 256 output cols) -> qls, kls
  {
    int cg = tid & 63, tc = tid >> 6;
    int o0 = cg * 4, t0 = tc * 16;
    float4 bi = *(const float4*)&bqk[o0];
    float acc[16][4];
#pragma unroll
    for (int t = 0; t < 16; ++t) { acc[t][0] = bi.x; acc[t][1] = bi.y; acc[t][2] = bi.z; acc[t][3] = bi.w; }
    for (int i = 0; i < 128; ++i) {
      const float* xr = &xs[i * 68 + t0];
      float xv[18];
#pragma unroll
      for (int u = 0; u < 18; ++u) xv[u] = xr[u];
#pragma unroll
      for (int j = 0; j < 3; ++j) {
        float4 w4 = *(const float4*)&wqkT[(j * 128 + i) * 256 + o0];
#pragma unroll
        for (int t = 0; t < 16; ++t) {
          float xvv = xv[t + j];
          acc[t][0] += xvv * w4.x; acc[t][1] += xvv * w4.y;
          acc[t][2] += xvv * w4.z; acc[t][3] += xvv * w4.w;
        }
      }
    }
    float* dst = (o0 < 128) ? qls : kls;
    int oo = o0 & 127;
#pragma unroll
    for (int t = 0; t < 16; ++t) {
      float4 r4; r4.x = acc[t][0]; r4.y = acc[t][1]; r4.z = acc[t][2]; r4.w = acc[t][3];
      *(float4*)&dst[(t0 + t) * 132 + oo] = r4;
    }
  }
  // ---- V GEMM (K = 128) -> vls
  {
    int cg = tid & 31, tc = tid >> 5;
    int o0 = cg * 4, t0 = tc * 8;
    float4 bi = *(const float4*)&b1f[o0];
    float acc[8][4];
#pragma unroll
    for (int t = 0; t < 8; ++t) { acc[t][0] = bi.x; acc[t][1] = bi.y; acc[t][2] = bi.z; acc[t][3] = bi.w; }
    for (int i = 0; i < 128; ++i) {
      const float* xr = &xs[i * 68 + t0 + 1];
      float4 w4 = *(const float4*)&w1T[i * 128 + o0];
#pragma unroll
      for (int t = 0; t < 8; ++t) {
        float xv = xr[t];
        acc[t][0] += xv * w4.x; acc[t][1] += xv * w4.y; acc[t][2] += xv * w4.z; acc[t][3] += xv * w4.w;
      }
    }
#pragma unroll
    for (int t = 0; t < 8; ++t) {
      float4 r4; r4.x = acc[t][0]; r4.y = acc[t][1]; r4.z = acc[t][2]; r4.w = acc[t][3];
      *(float4*)&vls[(t0 + t) * 132 + o0] = r4;
    }
  }
  __syncthreads();
  // ---- temporal attention, heads sequential; o overwrites q's own head cols
  for (int h = 0; h < 8; ++h) {
    int hb = h * 16;
    {
      int t0 = (tid >> 3) * 2, s0 = (tid & 7) * 8;
      float a[2][8] = {};
#pragma unroll
      for (int k = 0; k < 16; k += 4) {
        float4 q0 = *(float4*)&qls[t0 * 132 + hb + k];
        float4 q1 = *(float4*)&qls[(t0 + 1) * 132 + hb + k];
#pragma unroll
        for (int j = 0; j < 8; ++j) {
          float4 kk = *(float4*)&kls[(s0 + j) * 132 + hb + k];
          a[0][j] += q0.x * kk.x + q0.y * kk.y + q0.z * kk.z + q0.w * kk.w;
          a[1][j] += q1.x * kk.x + q1.y * kk.y + q1.z * kk.z + q1.w * kk.w;
        }
      }
#pragma unroll
      for (int i = 0; i < 2; ++i)
#pragma unroll
        for (int j = 0; j < 8; ++j) ss[(t0 + i) * 68 + s0 + j] = a[i][j] * 0.25f;
    }
    __syncthreads();
    int r = tid >> 2, g4 = tid & 3;
    float m = -1e30f;
    for (int u = 0; u < 16; ++u) m = fmaxf(m, ss[r * 68 + g4 * 16 + u]);
    red[tid] = m;
    __syncthreads();
    if (g4 == 0) mxr[r] = fmaxf(fmaxf(red[tid], red[tid + 1]), fmaxf(red[tid + 2], red[tid + 3]));
    __syncthreads();
    float sum = 0.f;
    for (int u = 0; u < 16; ++u) {
      int cix = g4 * 16 + u;
      float ev = __expf(ss[r * 68 + cix] - mxr[r]);
      ss[r * 68 + cix] = ev;
      sum += ev;
    }
    red[tid] = sum;
    __syncthreads();
    if (g4 == 0) invr[r] = 1.f / (red[tid] + red[tid + 1] + red[tid + 2] + red[tid + 3]);
    __syncthreads();
    {
      int t = tid >> 2, d0 = (tid & 3) * 4;
      float4 o4 = {0.f, 0.f, 0.f, 0.f};
      for (int s = 0; s < 64; ++s) {
        float w = ss[t * 68 + s];
        float4 v4 = *(float4*)&vls[s * 132 + hb + d0];
        o4.x += w * v4.x; o4.y += w * v4.y; o4.z += w * v4.z; o4.w += w * v4.w;
      }
      float iv = invr[t];
      o4.x *= iv; o4.y *= iv; o4.z *= iv; o4.w *= iv;
      *(float4*)&qls[t * 132 + hb + d0] = o4;
    }
    __syncthreads();
  }
  // ---- transpose o -> tr (reuse vls as [c*66 + t], 128*66 = 8448 fits exactly)
  float* tr = vls;
  for (int idx = tid; idx < TILE; idx += 256) {
    int t = idx >> 7, c = idx & 127;
    tr[c * 66 + t] = qls[t * 132 + c];
  }
  __syncthreads();
  // ---- w2 GEMM: ls[t][o] = sum_i o[t][i] * w2[o][i] + b2  -> kls
  {
    int cg = tid & 31, tc = tid >> 5;
    int o0 = cg * 4, t0 = tc * 8;
    float4 bi = *(const float4*)&b2f[o0];
    float acc[8][4];
#pragma unroll
    for (int t = 0; t < 8; ++t) { acc[t][0] = bi.x; acc[t][1] = bi.y; acc[t][2] = bi.z; acc[t][3] = bi.w; }
    for (int i = 0; i < 128; ++i) {
      const float* xr = &tr[i * 66 + t0];
      float4 w4 = *(const float4*)&w2T[i * 128 + o0];
#pragma unroll
      for (int t = 0; t < 8; ++t) {
        float xv = xr[t];
        acc[t][0] += xv * w4.x; acc[t][1] += xv * w4.y; acc[t][2] += xv * w4.z; acc[t][3] += xv * w4.w;
      }
    }
#pragma unroll
    for (int t = 0; t < 8; ++t) {
      float4 r4; r4.x = acc[t][0]; r4.y = acc[t][1]; r4.z = acc[t][2]; r4.w = acc[t][3];
      *(float4*)&kls[(t0 + t) * 132 + o0] = r4;
    }
  }
  __syncthreads();
  // ---- LN0 + residual -> xp (fp32)
  {
    int r = tid >> 2, sg = tid & 3;
    float s = 0.f, q2 = 0.f;
    for (int u = 0; u < 32; ++u) {
      float v = kls[r * 132 + sg * 32 + u];
      s += v; q2 += v * v;
    }
    red[tid] = s; red2[tid] = q2;
  }
  __syncthreads();
  if ((tid & 3) == 0) {
    int r = tid >> 2;
    float ssum = red[tid] + red[tid + 1] + red[tid + 2] + red[tid + 3];
    float qsum = red2[tid] + red2[tid + 1] + red2[tid + 2] + red2[tid + 3];
    float mm = ssum * (1.f / 128.f);
    mrow[r] = mm;
    vrow[r] = rsqrtf(qsum * (1.f / 128.f) - mm * mm + 1e-5f);
  }
  __syncthreads();
  float* dst = g0 + (size_t)bn * TILE;
  for (int idx = tid; idx < TILE; idx += 256) {
    int t = idx >> 7, c = idx & 127;
    dst[idx] = (kls[t * 132 + c] - mrow[t]) * vrow[t] * l0g[c] + l0b[c] + xs[c * 68 + t + 1];
  }
}

// ================================================================ megasp:
// per (b,t): spatial attention + Laplacian weighting + PV, fused theta GEMM +
// relu + LN1 + residual(xp) + e  -> h written fp32 IN PLACE over xp (each
// block touches only its own (b,*,t,*) slice).
__global__ __launch_bounds__(256, 1) void k_megasp(
    float* g0, const float* lap, const float* thT,
    const float* l1g, const float* l1b, const float* e) {
  int bt = blockIdx.x, b = bt >> 6, t = bt & 63;
  __shared__ float xts[256 * 132];  // 135168 B
  __shared__ float scs[16 * 260];   // 16640 B
  __shared__ float ybuf[16 * 132];  // 8448 B
  __shared__ float red[256], red2[256];
  __shared__ float mx[16], inv16[16], mrow[16], vrow[16];
  int tid = threadIdx.x;
  size_t base = (size_t)b * (N * (size_t)TILE) + (size_t)t * 128;
  for (int idx = tid * 4; idx < 32768; idx += 1024) {
    int n = idx >> 7, c = idx & 127;   // c multiple of 4
    float4 v4 = *(const float4*)&g0[base + (size_t)n * TILE + c];
    float* row = &xts[n * 132 + c];
    row[0] = v4.x; row[1] = v4.y; row[2] = v4.z; row[3] = v4.w;
  }
  __syncthreads();
  const float sc = 0.08838834764831845f;  // 1/sqrt(128)
  const float* eb = e + b * 128;
  for (int chunk = 0; chunk < 16; ++chunk) {
    int n0 = chunk * 16;
    // scores for 16 rows x 256 cols
    {
      int r0 = (tid >> 5) * 2, m0 = (tid & 31) * 8;
      float a[2][8] = {};
      for (int k = 0; k < 128; k += 4) {
        float4 q0 = *(float4*)&xts[(n0 + r0) * 132 + k];
        float4 q1 = *(float4*)&xts[(n0 + r0 + 1) * 132 + k];
#pragma unroll
        for (int j = 0; j < 8; ++j) {
          float4 mv = *(float4*)&xts[(m0 + j) * 132 + k];
          a[0][j] += q0.x * mv.x + q0.y * mv.y + q0.z * mv.z + q0.w * mv.w;
          a[1][j] += q1.x * mv.x + q1.y * mv.y + q1.z * mv.z + q1.w * mv.w;
        }
      }
#pragma unroll
      for (int i = 0; i < 2; ++i)
#pragma unroll
        for (int j = 0; j < 8; ++j) scs[(r0 + i) * 260 + m0 + j] = a[i][j] * sc;
    }
    __syncthreads();
    int r = tid >> 4, sg = tid & 15;
    float m = -1e30f;
    for (int u = 0; u < 16; ++u) m = fmaxf(m, scs[r * 260 + sg * 16 + u]);
    red[tid] = m;
    __syncthreads();
    if (tid < 16) {
      float mm = red[tid * 16];
      for (int u = 1; u < 16; ++u) mm = fmaxf(mm, red[tid * 16 + u]);
      mx[tid] = mm;
    }
    __syncthreads();
    float s = 0.f;
    for (int u = 0; u < 16; ++u) {
      int cix = sg * 16 + u;
      float ev = __expf(scs[r * 260 + cix] - mx[r]);
      scs[r * 260 + cix] = ev;
      s += ev;
    }
    red[tid] = s;
    __syncthreads();
    if (tid < 16) {
      float ssum = 0.f;
      for (int u = 0; u < 16; ++u) ssum += red[tid * 16 + u];
      inv16[tid] = 1.f / ssum;
    }
    __syncthreads();
    for (int idx = tid; idx < 4096; idx += 256) {
      int rr = idx >> 8, m2 = idx & 255;
      scs[rr * 260 + m2] *= inv16[rr] * lap[(n0 + rr) * 256 + m2] * sc;
    }
    __syncthreads();
    // PV -> ybuf (16 x 128)
    {
      int rr = tid >> 4, c0 = (tid & 15) * 8;
      float4 ya = {0.f, 0.f, 0.f, 0.f}, yb = {0.f, 0.f, 0.f, 0.f};
      for (int m2 = 0; m2 < 256; ++m2) {
        float w = scs[rr * 260 + m2];
        float4 xa = *(float4*)&xts[m2 * 132 + c0];
        float4 xb4 = *(float4*)&xts[m2 * 132 + c0 + 4];
        ya.x += w * xa.x; ya.y += w * xa.y; ya.z += w * xa.z; ya.w += w * xa.w;
        yb.x += w * xb4.x; yb.y += w * xb4.y; yb.z += w * xb4.z; yb.w += w * xb4.w;
      }
      *(float4*)&ybuf[rr * 132 + c0] = ya;
      *(float4*)&ybuf[rr * 132 + c0 + 4] = yb;
    }
    __syncthreads();
    // theta GEMM + relu + LN1 partials
    float acc[8];
    {
      int rr = tid >> 4, o0 = (tid & 15) * 8;
#pragma unroll
      for (int u = 0; u < 8; ++u) acc[u] = 0.f;
      for (int i = 0; i < 128; ++i) {
        float yv = ybuf[rr * 132 + i];
        float4 wa = *(const float4*)&thT[i * 128 + o0];
        float4 wb = *(const float4*)&thT[i * 128 + o0 + 4];
        acc[0] += yv * wa.x; acc[1] += yv * wa.y; acc[2] += yv * wa.z; acc[3] += yv * wa.w;
        acc[4] += yv * wb.x; acc[5] += yv * wb.y; acc[6] += yv * wb.z; acc[7] += yv * wb.w;
      }
      float sps = 0.f, spq = 0.f;
#pragma unroll
      for (int u = 0; u < 8; ++u) {
        acc[u] = fmaxf(acc[u], 0.f);
        sps += acc[u]; spq += acc[u] * acc[u];
      }
      red[tid] = sps; red2[tid] = spq;
    }
    __syncthreads();
    if (tid < 16) {
      float ssum = 0.f, qsum = 0.f;
      for (int u = 0; u < 16; ++u) { ssum += red[tid * 16 + u]; qsum += red2[tid * 16 + u]; }
      float mm = ssum * (1.f / 128.f);
      mrow[tid] = mm;
      vrow[tid] = rsqrtf(qsum * (1.f / 128.f) - mm * mm + 1e-5f);
    }
    __syncthreads();
    // h = xp + LN1(y1) + e  -> in place (fp32)
    {
      int rr = tid >> 4, o0 = (tid & 15) * 8;
      int n = n0 + rr;
      float mm = mrow[rr], vv = vrow[rr];
#pragma unroll
      for (int u = 0; u < 8; ++u) {
        int c = o0 + u;
        float hv = (acc[u] - mm) * vv * l1g[c] + l1b[c] + xts[n * 132 + c] + eb[c];
        g0[base + (size_t)n * TILE + c] = hv;
      }
    }
    __syncthreads();
  }
}

// ================================================================ megadec:
// per (b,n): h -> ec conv, xh conv, c1 conv(ec), sigmoid gate, relu,
// 128->2 projection -> d_out (dtype per flag).
__global__ __launch_bounds__(256, 2) void k_megadec(
    const float* g0, const float* dxcT, const float* dxcb,
    const float* decT, const float* decb, const float* dc1T, const float* dc1b,
    const float* dp2w, const float* dp2b, const int* flag, void* outv) {
  int bn = blockIdx.x, b = bn >> 8, n = bn & 255;
  int f32o = flag[0];
  __shared__ float hs[128 * 68];    // h [c][t+1]; later out_pre [c][t]
  __shared__ float ecs[128 * 68];   // ec [c][t+1]
  __shared__ float p0[256], p1[256];
  int tid = threadIdx.x;
  const float* gp = g0 + (size_t)bn * TILE;
  for (int idx = tid * 4; idx < TILE; idx += 1024) {
    int t = idx >> 7, c = idx & 127;   // c multiple of 4
    float4 v4 = *(const float4*)&gp[idx];
    hs[(c + 0) * 68 + t + 1] = v4.x;
    hs[(c + 1) * 68 + t + 1] = v4.y;
    hs[(c + 2) * 68 + t + 1] = v4.z;
    hs[(c + 3) * 68 + t + 1] = v4.w;
  }
  if (tid < 128) {
    hs[tid * 68] = 0.f; hs[tid * 68 + 65] = 0.f;
    ecs[tid * 68] = 0.f; ecs[tid * 68 + 65] = 0.f;
  }
  __syncthreads();
  int cg = tid & 31, tc = tid >> 5;
  int o0 = cg * 4, t0 = tc * 8;
  // ---- ec = conv(h, dec) -> ecs [c][t+1]
  {
    float4 bi = *(const float4*)&decb[o0];
    float acc[8][4];
#pragma unroll
    for (int t = 0; t < 8; ++t) { acc[t][0] = bi.x; acc[t][1] = bi.y; acc[t][2] = bi.z; acc[t][3] = bi.w; }
    for (int i = 0; i < 128; ++i) {
      const float* xr = &hs[i * 68 + t0];
      float xv[10];
#pragma unroll
      for (int u = 0; u < 10; ++u) xv[u] = xr[u];
#pragma unroll
      for (int j = 0; j < 3; ++j) {
        float4 w4 = *(const float4*)&decT[(j * 128 + i) * 128 + o0];
#pragma unroll
        for (int t = 0; t < 8; ++t) {
          float xvv = xv[t + j];
          acc[t][0] += xvv * w4.x; acc[t][1] += xvv * w4.y;
          acc[t][2] += xvv * w4.z; acc[t][3] += xvv * w4.w;
        }
      }
    }
#pragma unroll
    for (int t = 0; t < 8; ++t)
#pragma unroll
      for (int z = 0; z < 4; ++z) ecs[(o0 + z) * 68 + (t0 + t) + 1] = acc[t][z];
  }
  __syncthreads();
  // ---- xh = conv(h, dxc);  c1 = conv(ec, dc1);  combine
  float accx[8][4], accc[8][4];
  {
    float4 bx = *(const float4*)&dxcb[o0];
    float4 bc = *(const float4*)&dc1b[o0];
#pragma unroll
    for (int t = 0; t < 8; ++t) {
      accx[t][0] = bx.x; accx[t][1] = bx.y; accx[t][2] = bx.z; accx[t][3] = bx.w;
      accc[t][0] = bc.x; accc[t][1] = bc.y; accc[t][2] = bc.z; accc[t][3] = bc.w;
    }
    for (int i = 0; i < 128; ++i) {
      const float* hr = &hs[i * 68 + t0];
      const float* er = &ecs[i * 68 + t0];
      float xvh[10], xvc[10];
#pragma unroll
      for (int u = 0; u < 10; ++u) { xvh[u] = hr[u]; xvc[u] = er[u]; }
#pragma unroll
      for (int j = 0; j < 3; ++j) {
        float4 wx = *(const float4*)&dxcT[(j * 128 + i) * 128 + o0];
        float4 wc = *(const float4*)&dc1T[(j * 128 + i) * 128 + o0];
#pragma unroll
        for (int t = 0; t < 8; ++t) {
          float hv = xvh[t + j], ev = xvc[t + j];
          accx[t][0] += hv * wx.x; accx[t][1] += hv * wx.y;
          accx[t][2] += hv * wx.z; accx[t][3] += hv * wx.w;
          accc[t][0] += ev * wc.x; accc[t][1] += ev * wc.y;
          accc[t][2] += ev * wc.z; accc[t][3] += ev * wc.w;
        }
      }
    }
#pragma unroll
    for (int t = 0; t < 8; ++t) {
      int row = t0 + t;
#pragma unroll
      for (int z = 0; z < 4; ++z) {
        float ecv = ecs[(o0 + z) * 68 + row + 1];
        accx[t][z] = fmaxf(accx[t][z] + sigm(ecv) + accc[t][z], 0.f);
      }
    }
  }
  __syncthreads();  // all hs reads done before overwrite
  // store out_pre into hs as [c][t]
#pragma unroll
  for (int t = 0; t < 8; ++t)
#pragma unroll
    for (int z = 0; z < 4; ++z) hs[(o0 + z) * 68 + (t0 + t)] = accx[t][z];
  __syncthreads();
  // ---- projection 128 -> 2
  int tt = tid >> 2, sg4 = tid & 3;
  float a0 = 0.f, a1 = 0.f;
  for (int u = 0; u < 32; ++u) {
    int c = sg4 * 32 + u;
    float v = hs[c * 68 + tt];
    a0 += v * dp2w[c];
    a1 += v * dp2w[128 + c];
  }
  p0[tid] = a0; p1[tid] = a1;
  __syncthreads();
  if (sg4 == 0) {
    float o0v = p0[tid] + p0[tid + 1] + p0[tid + 2] + p0[tid + 3] + dp2b[0];
    float o1v = p1[tid] + p1[tid + 1] + p1[tid + 2] + p1[tid + 3] + dp2b[1];
    size_t i0 = ((size_t)(b * 2 + 0) * 256 + n) * 64 + tt;
    size_t i1 = ((size_t)(b * 2 + 1) * 256 + n) * 64 + tt;
    if (f32o) {
      ((float*)outv)[i0] = o0v;
      ((float*)outv)[i1] = o1v;
    } else {
      ((__hip_bfloat16*)outv)[i0] = __float2bfloat16(o0v);
      ((__hip_bfloat16*)outv)[i1] = __float2bfloat16(o1v);
    }
  }
}

}  // namespace

extern "C" void kernel_launch(void* const* d_in, const int* in_sizes, int n_in,
                              void* d_out, int out_size, void* d_ws, size_t ws_size,
                              hipStream_t stream) {
  (void)in_sizes; (void)n_in; (void)out_size; (void)ws_size;
  const void* x    = d_in[0];
  const void* adj  = d_in[1];
  const int*  step = (const int*)d_in[2];
  const void* wq   = d_in[3];
  const void* bq   = d_in[4];
  const void* wk   = d_in[5];
  const void* bk   = d_in[6];
  const void* w1   = d_in[7];
  const void* b1   = d_in[8];
  const void* w2   = d_in[9];
  const void* b2   = d_in[10];
  const void* th   = d_in[11];
  const void* l0g  = d_in[12];
  const void* l0b  = d_in[13];
  const void* l1g  = d_in[14];
  const void* l1b  = d_in[15];
  const void* p1w  = d_in[16];
  const void* p1b  = d_in[17];
  const void* p2w  = d_in[18];
  const void* p2b  = d_in[19];
  const void* dxcw = d_in[20];
  const void* dxcb = d_in[21];
  const void* decw = d_in[22];
  const void* decb = d_in[23];
  const void* dc1w = d_in[24];
  const void* dc1b = d_in[25];
  const void* dp2w = d_in[26];
  const void* dp2b = d_in[27];

  // ---- workspace layout: flag + fp32 params, then xf (fp32 x), then g0 (fp32)
  float* ws = (float*)d_ws;
  int* flag = (int*)ws;
  float* p = ws + 16;
  float* e     = p; p += 1024;
  float* lap   = p; p += 65536;
  float* wqkT  = p; p += 98304;
  float* w1T   = p; p += 16384;
  float* w2T   = p; p += 16384;
  float* thT   = p; p += 16384;
  float* dxcT  = p; p += 49152;
  float* decT  = p; p += 49152;
  float* dc1T  = p; p += 49152;
  float* bqk   = p; p += 256;
  float* b1f   = p; p += 128;
  float* b2f   = p; p += 128;
  float* l0gf  = p; p += 128;
  float* l0bf  = p; p += 128;
  float* l1gf  = p; p += 128;
  float* l1bf  = p; p += 128;
  float* dxcbf = p; p += 128;
  float* decbf = p; p += 128;
  float* dc1bf = p; p += 128;
  float* dp2wf = p; p += 256;
  float* dp2bf = p; p += 8;
  size_t off = (size_t)(p - ws);
  off = (off + 127) & ~(size_t)127;
  float* xf = ws + off;            // BIGE floats (67 MB)
  float* g0 = xf + BIGE;           // BIGE floats (67 MB)

  PrepArgs pa;
  pa.flag = flag;
  pa.wq = wq; pa.wk = wk; pa.w1 = w1; pa.w2 = w2; pa.th = th;
  pa.dxc = dxcw; pa.dec = decw; pa.dc1 = dc1w;
  pa.bq = bq; pa.bk = bk; pa.b1 = b1; pa.b2 = b2;
  pa.l0g = l0g; pa.l0b = l0b; pa.l1g = l1g; pa.l1b = l1b;
  pa.dxcb = dxcb; pa.decb = decb; pa.dc1b = dc1b; pa.dp2w = dp2w; pa.dp2b = dp2b;
  pa.wqkT = wqkT; pa.w1T = w1T; pa.w2T = w2T; pa.thT = thT;
  pa.dxcT = dxcT; pa.decT = decT; pa.dc1T = dc1T;
  pa.bqk = bqk; pa.b1f = b1f; pa.b2f = b2f;
  pa.l0gf = l0gf; pa.l0bf = l0bf; pa.l1gf = l1gf; pa.l1bf = l1bf;
  pa.dxcbf = dxcbf; pa.decbf = decbf; pa.dc1bf = dc1bf; pa.dp2wf = dp2wf; pa.dp2bf = dp2bf;

  k_sniff<<<1, 64, 0, stream>>>((const unsigned short*)x, flag);
  k_cvtx<<<1024, 256, 0, stream>>>(x, flag, xf);
  k_prep<<<128, 256, 0, stream>>>(pa);
  k_lap<<<1, 256, 0, stream>>>(adj, flag, lap);
  k_emb<<<8, 128, 0, stream>>>(step, flag, p1w, p1b, p2w, p2b, e);

  k_mega1<<<2048, 256, 0, stream>>>(xf, wqkT, bqk, w1T, b1f, w2T, b2f, l0gf, l0bf, g0);
  k_megasp<<<512, 256, 0, stream>>>(g0, lap, thT, l1gf, l1bf, e);
  k_megadec<<<2048, 256, 0, stream>>>(g0, dxcT, dxcbf, decT, decbf, dc1T, dc1bf,
                                      dp2wf, dp2bf, flag, d_out);
}

// Round 4
// 2095.198 us; speedup vs baseline: 1.2414x; 1.2414x over previous
//
#include <hip/hip_runtime.h>
#include <hip/hip_bf16.h>

namespace {

constexpr int C = 128, N = 256, T = 64, Bsz = 8;
constexpr int TILE = T * C;                       // 8192 elements per (b,n) slab
constexpr size_t BIGE = (size_t)Bsz * N * T * C;  // 16,777,216 elements

__device__ __forceinline__ float bfu(unsigned short u) {
  unsigned int x = ((unsigned int)u) << 16;
  return __uint_as_float(x);
}
// flag-aware load: f32 != 0 -> input is fp32, else bf16
__device__ __forceinline__ float ld(const void* p, size_t i, int f32) {
  if (f32) return ((const float*)p)[i];
  return bfu(((const unsigned short*)p)[i]);
}
__device__ __forceinline__ float sigm(float x) { return 1.f / (1.f + __expf(-x)); }

// ---------------------------------------------------------------- dtype sniffer
__global__ __launch_bounds__(64) void k_sniff(const unsigned short* x, int* flag) {
  __shared__ int cnt[64];
  int tid = threadIdx.x;
  int c = 0;
  for (int u = 0; u < 8; ++u) {
    unsigned short v = x[tid * 8 + u];
    int e = (v >> 7) & 255;
    c += (e >= 97 && e <= 157) ? 1 : 0;
  }
  cnt[tid] = c;
  __syncthreads();
  if (tid == 0) {
    int s = 0;
    for (int i = 0; i < 64; ++i) s += cnt[i];
    flag[0] = (s < 435) ? 1 : 0;  // <85% plausible-bf16 words -> fp32 input
  }
}

// ---------------------------------------------------------------- x -> fp32 copy
__global__ __launch_bounds__(256) void k_cvtx(const void* x, const int* flag, float* xf) {
  int f = flag[0];
  size_t i0 = ((size_t)blockIdx.x * 256 + threadIdx.x) * 4;
  size_t stride = (size_t)gridDim.x * 1024;
  if (f) {
    const float4* src = (const float4*)x;
    for (size_t i = i0; i < BIGE; i += stride) *(float4*)&xf[i] = src[i >> 2];
  } else {
    const ushort4* src = (const ushort4*)x;
    for (size_t i = i0; i < BIGE; i += stride) {
      ushort4 u = src[i >> 2];
      float4 v; v.x = bfu(u.x); v.y = bfu(u.y); v.z = bfu(u.z); v.w = bfu(u.w);
      *(float4*)&xf[i] = v;
    }
  }
}

// ---------------------------------------------------------------- prep (weights -> fp32, k-major)
struct PrepArgs {
  const int* flag;
  const void *wq, *wk, *w1, *w2, *th, *dxc, *dec, *dc1;
  const void *bq, *bk, *b1, *b2, *l0g, *l0b, *l1g, *l1b, *dxcb, *decb, *dc1b, *dp2w, *dp2b;
  float *wqkT, *w1T, *w2T, *thT, *dxcT, *decT, *dc1T;
  float *bqk, *b1f, *b2f, *l0gf, *l0bf, *l1gf, *l1bf, *dxcbf, *decbf, *dc1bf, *dp2wf, *dp2bf;
};

__global__ __launch_bounds__(256) void k_prep(PrepArgs a) {
  int f = a.flag[0];
  int idx = blockIdx.x * blockDim.x + threadIdx.x;
  int stride = gridDim.x * blockDim.x;
  for (int i = idx; i < 384 * 256; i += stride) {
    int k = i >> 8, o = i & 255, j = k >> 7, ii = k & 127;
    a.wqkT[i] = (o < 128) ? ld(a.wq, (o * 128 + ii) * 3 + j, f)
                          : ld(a.wk, ((o - 128) * 128 + ii) * 3 + j, f);
  }
  for (int i = idx; i < 16384; i += stride) {
    int k = i >> 7, o = i & 127;
    a.w1T[i] = ld(a.w1, o * 128 + k, f);
    a.w2T[i] = ld(a.w2, o * 128 + k, f);
    a.thT[i] = ld(a.th, o * 128 + k, f);
  }
  for (int i = idx; i < 384 * 128; i += stride) {
    int k = i >> 7, o = i & 127, j = k >> 7, ii = k & 127;
    int s = (o * 128 + ii) * 3 + j;
    a.dxcT[i] = ld(a.dxc, s, f); a.decT[i] = ld(a.dec, s, f); a.dc1T[i] = ld(a.dc1, s, f);
  }
  for (int i = idx; i < 256; i += stride) {
    a.bqk[i] = (i < 128) ? ld(a.bq, i, f) : ld(a.bk, i - 128, f);
    a.dp2wf[i] = ld(a.dp2w, i, f);
  }
  for (int i = idx; i < 128; i += stride) {
    a.b1f[i] = ld(a.b1, i, f);   a.b2f[i] = ld(a.b2, i, f);
    a.l0gf[i] = ld(a.l0g, i, f); a.l0bf[i] = ld(a.l0b, i, f);
    a.l1gf[i] = ld(a.l1g, i, f); a.l1bf[i] = ld(a.l1b, i, f);
    a.dxcbf[i] = ld(a.dxcb, i, f); a.decbf[i] = ld(a.decb, i, f); a.dc1bf[i] = ld(a.dc1b, i, f);
  }
  if (idx < 2) a.dp2bf[idx] = ld(a.dp2b, idx, f);
}

__global__ __launch_bounds__(256) void k_lap(const void* adj, const int* flag, float* lap) {
  __shared__ float dsh[256];
  int f = flag[0];
  int tid = threadIdx.x;
  float s = 0.f;
  for (int m = 0; m < 256; ++m) s += ld(adj, tid * 256 + m, f);
  dsh[tid] = 1.f / sqrtf(s);
  __syncthreads();
  for (int idx = tid; idx < 65536; idx += 256) {
    int n = idx >> 8, m = idx & 255;
    lap[idx] = ld(adj, idx, f) * dsh[n] * dsh[m];
  }
}

__global__ __launch_bounds__(128) void k_emb(const int* step, const int* flag,
                                             const void* p1w, const void* p1b,
                                             const void* p2w, const void* p2b, float* e) {
  int b = blockIdx.x, c = threadIdx.x;
  int f = flag[0];
  __shared__ float tab[128], e1[128];
  float sv = (float)step[b];
  int i0 = c & 63;
  float fr = powf(10.f, (float)i0 / 63.f * 4.f);
  float ang = sv * fr;
  tab[c] = (c < 64) ? sinf(ang) : cosf(ang);
  __syncthreads();
  float a = ld(p1b, c, f);
  for (int i = 0; i < 128; ++i) a += tab[i] * ld(p1w, c * 128 + i, f);
  a = a * sigm(a);
  e1[c] = a;
  __syncthreads();
  float a2 = ld(p2b, c, f);
  for (int i = 0; i < 128; ++i) a2 += e1[i] * ld(p2w, c * 128 + i, f);
  e[b * 128 + c] = a2 * sigm(a2);
}

// ================================================================ mega1 (unchanged):
__global__ __launch_bounds__(256, 1) void k_mega1(
    const float* xf, const float* wqkT, const float* bqk,
    const float* w1T, const float* b1f, const float* w2T, const float* b2f,
    const float* l0g, const float* l0b, float* g0) {
  int bn = blockIdx.x, b = bn >> 8, n = bn & 255;
  __shared__ float xs[128 * 68];
  __shared__ float qls[64 * 132];
  __shared__ float kls[64 * 132];
  __shared__ float vls[64 * 132];
  __shared__ float ss[64 * 68];
  __shared__ float red[256], red2[256];
  __shared__ float mxr[64], invr[64], mrow[64], vrow[64];
  int tid = threadIdx.x;
  const float* xb = xf + (size_t)b * C * N * T + (size_t)n * T;
  for (int idx = tid * 4; idx < TILE; idx += 1024) {
    int i = idx >> 6, t = idx & 63;
    float4 v4 = *(const float4*)&xb[(size_t)i * N * T + t];
    float* row = &xs[i * 68 + t + 1];
    row[0] = v4.x; row[1] = v4.y; row[2] = v4.z; row[3] = v4.w;
  }
  if (tid < 128) { xs[tid * 68] = 0.f; xs[tid * 68 + 65] = 0.f; }
  __syncthreads();
  {
    int cg = tid & 63, tc = tid >> 6;
    int o0 = cg * 4, t0 = tc * 16;
    float4 bi = *(const float4*)&bqk[o0];
    float acc[16][4];
#pragma unroll
    for (int t = 0; t < 16; ++t) { acc[t][0] = bi.x; acc[t][1] = bi.y; acc[t][2] = bi.z; acc[t][3] = bi.w; }
    for (int i = 0; i < 128; ++i) {
      const float* xr = &xs[i * 68 + t0];
      float xv[18];
#pragma unroll
      for (int u = 0; u < 18; ++u) xv[u] = xr[u];
#pragma unroll
      for (int j = 0; j < 3; ++j) {
        float4 w4 = *(const float4*)&wqkT[(j * 128 + i) * 256 + o0];
#pragma unroll
        for (int t = 0; t < 16; ++t) {
          float xvv = xv[t + j];
          acc[t][0] += xvv * w4.x; acc[t][1] += xvv * w4.y;
          acc[t][2] += xvv * w4.z; acc[t][3] += xvv * w4.w;
        }
      }
    }
    float* dst = (o0 < 128) ? qls : kls;
    int oo = o0 & 127;
#pragma unroll
    for (int t = 0; t < 16; ++t) {
      float4 r4; r4.x = acc[t][0]; r4.y = acc[t][1]; r4.z = acc[t][2]; r4.w = acc[t][3];
      *(float4*)&dst[(t0 + t) * 132 + oo] = r4;
    }
  }
  {
    int cg = tid & 31, tc = tid >> 5;
    int o0 = cg * 4, t0 = tc * 8;
    float4 bi = *(const float4*)&b1f[o0];
    float acc[8][4];
#pragma unroll
    for (int t = 0; t < 8; ++t) { acc[t][0] = bi.x; acc[t][1] = bi.y; acc[t][2] = bi.z; acc[t][3] = bi.w; }
    for (int i = 0; i < 128; ++i) {
      const float* xr = &xs[i * 68 + t0 + 1];
      float4 w4 = *(const float4*)&w1T[i * 128 + o0];
#pragma unroll
      for (int t = 0; t < 8; ++t) {
        float xv = xr[t];
        acc[t][0] += xv * w4.x; acc[t][1] += xv * w4.y; acc[t][2] += xv * w4.z; acc[t][3] += xv * w4.w;
      }
    }
#pragma unroll
    for (int t = 0; t < 8; ++t) {
      float4 r4; r4.x = acc[t][0]; r4.y = acc[t][1]; r4.z = acc[t][2]; r4.w = acc[t][3];
      *(float4*)&vls[(t0 + t) * 132 + o0] = r4;
    }
  }
  __syncthreads();
  for (int h = 0; h < 8; ++h) {
    int hb = h * 16;
    {
      int t0 = (tid >> 3) * 2, s0 = (tid & 7) * 8;
      float a[2][8] = {};
#pragma unroll
      for (int k = 0; k < 16; k += 4) {
        float4 q0 = *(float4*)&qls[t0 * 132 + hb + k];
        float4 q1 = *(float4*)&qls[(t0 + 1) * 132 + hb + k];
#pragma unroll
        for (int j = 0; j < 8; ++j) {
          float4 kk = *(float4*)&kls[(s0 + j) * 132 + hb + k];
          a[0][j] += q0.x * kk.x + q0.y * kk.y + q0.z * kk.z + q0.w * kk.w;
          a[1][j] += q1.x * kk.x + q1.y * kk.y + q1.z * kk.z + q1.w * kk.w;
        }
      }
#pragma unroll
      for (int i = 0; i < 2; ++i)
#pragma unroll
        for (int j = 0; j < 8; ++j) ss[(t0 + i) * 68 + s0 + j] = a[i][j] * 0.25f;
    }
    __syncthreads();
    int r = tid >> 2, g4 = tid & 3;
    float m = -1e30f;
    for (int u = 0; u < 16; ++u) m = fmaxf(m, ss[r * 68 + g4 * 16 + u]);
    red[tid] = m;
    __syncthreads();
    if (g4 == 0) mxr[r] = fmaxf(fmaxf(red[tid], red[tid + 1]), fmaxf(red[tid + 2], red[tid + 3]));
    __syncthreads();
    float sum = 0.f;
    for (int u = 0; u < 16; ++u) {
      int cix = g4 * 16 + u;
      float ev = __expf(ss[r * 68 + cix] - mxr[r]);
      ss[r * 68 + cix] = ev;
      sum += ev;
    }
    red[tid] = sum;
    __syncthreads();
    if (g4 == 0) invr[r] = 1.f / (red[tid] + red[tid + 1] + red[tid + 2] + red[tid + 3]);
    __syncthreads();
    {
      int t = tid >> 2, d0 = (tid & 3) * 4;
      float4 o4 = {0.f, 0.f, 0.f, 0.f};
      for (int s = 0; s < 64; ++s) {
        float w = ss[t * 68 + s];
        float4 v4 = *(float4*)&vls[s * 132 + hb + d0];
        o4.x += w * v4.x; o4.y += w * v4.y; o4.z += w * v4.z; o4.w += w * v4.w;
      }
      float iv = invr[t];
      o4.x *= iv; o4.y *= iv; o4.z *= iv; o4.w *= iv;
      *(float4*)&qls[t * 132 + hb + d0] = o4;
    }
    __syncthreads();
  }
  float* tr = vls;
  for (int idx = tid; idx < TILE; idx += 256) {
    int t = idx >> 7, c = idx & 127;
    tr[c * 66 + t] = qls[t * 132 + c];
  }
  __syncthreads();
  {
    int cg = tid & 31, tc = tid >> 5;
    int o0 = cg * 4, t0 = tc * 8;
    float4 bi = *(const float4*)&b2f[o0];
    float acc[8][4];
#pragma unroll
    for (int t = 0; t < 8; ++t) { acc[t][0] = bi.x; acc[t][1] = bi.y; acc[t][2] = bi.z; acc[t][3] = bi.w; }
    for (int i = 0; i < 128; ++i) {
      const float* xr = &tr[i * 66 + t0];
      float4 w4 = *(const float4*)&w2T[i * 128 + o0];
#pragma unroll
      for (int t = 0; t < 8; ++t) {
        float xv = xr[t];
        acc[t][0] += xv * w4.x; acc[t][1] += xv * w4.y; acc[t][2] += xv * w4.z; acc[t][3] += xv * w4.w;
      }
    }
#pragma unroll
    for (int t = 0; t < 8; ++t) {
      float4 r4; r4.x = acc[t][0]; r4.y = acc[t][1]; r4.z = acc[t][2]; r4.w = acc[t][3];
      *(float4*)&kls[(t0 + t) * 132 + o0] = r4;
    }
  }
  __syncthreads();
  {
    int r = tid >> 2, sg = tid & 3;
    float s = 0.f, q2 = 0.f;
    for (int u = 0; u < 32; ++u) {
      float v = kls[r * 132 + sg * 32 + u];
      s += v; q2 += v * v;
    }
    red[tid] = s; red2[tid] = q2;
  }
  __syncthreads();
  if ((tid & 3) == 0) {
    int r = tid >> 2;
    float ssum = red[tid] + red[tid + 1] + red[tid + 2] + red[tid + 3];
    float qsum = red2[tid] + red2[tid + 1] + red2[tid + 2] + red2[tid + 3];
    float mm = ssum * (1.f / 128.f);
    mrow[r] = mm;
    vrow[r] = rsqrtf(qsum * (1.f / 128.f) - mm * mm + 1e-5f);
  }
  __syncthreads();
  float* dst = g0 + (size_t)bn * TILE;
  for (int idx = tid; idx < TILE; idx += 256) {
    int t = idx >> 7, c = idx & 127;
    dst[idx] = (kls[t * 132 + c] - mrow[t]) * vrow[t] * l0g[c] + l0b[c] + xs[c * 68 + t + 1];
  }
}

// ================================================================ megasp v2:
// per (b,t), 512 threads. Scores kept in registers through softmax (butterfly
// shuffles, width 32 = one row); scs written once (pre-weighted), read once.
// Conflict-free-ish mappings: score m-reads stride-32 rows, PV lane-consecutive.
__global__ __launch_bounds__(512, 1) void k_megasp(
    float* g0, const float* lap, const float* thT,
    const float* l1g, const float* l1b, const float* e) {
  int bt = blockIdx.x, b = bt >> 6, t = bt & 63;
  __shared__ float xts[256 * 132];  // 135168 B  (xp slab, [n][c], stride 132)
  __shared__ float scs[16 * 260];   // 16640 B   (weighted attention, one chunk)
  __shared__ float ybuf[16 * 132];  // 8448 B    (PV output, one chunk)
  int tid = threadIdx.x;
  size_t base = (size_t)b * (N * (size_t)TILE) + (size_t)t * 128;
  for (int idx = tid * 4; idx < 32768; idx += 2048) {
    int n = idx >> 7, c = idx & 127;
    float4 v4 = *(const float4*)&g0[base + (size_t)n * TILE + c];
    *(float4*)&xts[n * 132 + c] = v4;
  }
  __syncthreads();
  const float sc = 0.08838834764831845f;  // 1/sqrt(128)
  const float* eb = e + b * 128;
  int r = tid >> 5;          // 0..15 (row within chunk)
  int sg = tid & 31;         // lane-in-row
  int oc = sg * 4;           // theta/PV column base (0..124)*4
  // hoist per-thread constants
  float4 g4 = *(const float4*)&l1g[oc];
  float4 bb4 = *(const float4*)&l1b[oc];
  float4 e4 = *(const float4*)&eb[oc];
  for (int chunk = 0; chunk < 16; ++chunk) {
    int n0 = chunk * 16;
    int n = n0 + r;
    // ---- scores for row n vs all 256 cols, in registers
    float a[8];
#pragma unroll
    for (int jj = 0; jj < 8; ++jj) a[jj] = 0.f;
    const float* qrow = &xts[n * 132];
    for (int k = 0; k < 128; k += 4) {
      float4 q4 = *(const float4*)&qrow[k];
#pragma unroll
      for (int jj = 0; jj < 8; ++jj) {
        const float4 m4 = *(const float4*)&xts[(sg + 32 * jj) * 132 + k];
        a[jj] += q4.x * m4.x + q4.y * m4.y + q4.z * m4.z + q4.w * m4.w;
      }
    }
    float mloc = -1e30f;
#pragma unroll
    for (int jj = 0; jj < 8; ++jj) { a[jj] *= sc; mloc = fmaxf(mloc, a[jj]); }
#pragma unroll
    for (int s = 16; s > 0; s >>= 1) mloc = fmaxf(mloc, __shfl_xor(mloc, s, 32));
    float ssum = 0.f;
#pragma unroll
    for (int jj = 0; jj < 8; ++jj) { a[jj] = __expf(a[jj] - mloc); ssum += a[jj]; }
#pragma unroll
    for (int s = 16; s > 0; s >>= 1) ssum += __shfl_xor(ssum, s, 32);
    float inv = sc / ssum;   // softmax * sc folded
    const float* lrow = &lap[n * 256];
#pragma unroll
    for (int jj = 0; jj < 8; ++jj) {
      int m = sg + 32 * jj;
      scs[r * 260 + m] = a[jj] * inv * lrow[m];
    }
    __syncthreads();
    // ---- PV: y[r][oc..oc+3] = sum_m w[r][m] * x[m][oc..]
    {
      float4 acc = {0.f, 0.f, 0.f, 0.f};
      const float* srow = &scs[r * 260];
      for (int m2 = 0; m2 < 256; ++m2) {
        float w = srow[m2];
        float4 x4 = *(const float4*)&xts[m2 * 132 + oc];
        acc.x += w * x4.x; acc.y += w * x4.y; acc.z += w * x4.z; acc.w += w * x4.w;
      }
      *(float4*)&ybuf[r * 132 + oc] = acc;
    }
    __syncthreads();
    // ---- theta GEMM + relu + LN1 + residual + e -> h (global, in place)
    {
      float4 acc = {0.f, 0.f, 0.f, 0.f};
      const float* yrow = &ybuf[r * 132];
      for (int i = 0; i < 128; ++i) {
        float yv = yrow[i];
        float4 w4 = *(const float4*)&thT[i * 128 + oc];
        acc.x += yv * w4.x; acc.y += yv * w4.y; acc.z += yv * w4.z; acc.w += yv * w4.w;
      }
      acc.x = fmaxf(acc.x, 0.f); acc.y = fmaxf(acc.y, 0.f);
      acc.z = fmaxf(acc.z, 0.f); acc.w = fmaxf(acc.w, 0.f);
      float sps = acc.x + acc.y + acc.z + acc.w;
      float spq = acc.x * acc.x + acc.y * acc.y + acc.z * acc.z + acc.w * acc.w;
#pragma unroll
      for (int s = 16; s > 0; s >>= 1) {
        sps += __shfl_xor(sps, s, 32);
        spq += __shfl_xor(spq, s, 32);
      }
      float mm = sps * (1.f / 128.f);
      float rs = rsqrtf(spq * (1.f / 128.f) - mm * mm + 1e-5f);
      const float* xr = &xts[n * 132 + oc];
      float4 hv;
      hv.x = (acc.x - mm) * rs * g4.x + bb4.x + xr[0] + e4.x;
      hv.y = (acc.y - mm) * rs * g4.y + bb4.y + xr[1] + e4.y;
      hv.z = (acc.z - mm) * rs * g4.z + bb4.z + xr[2] + e4.z;
      hv.w = (acc.w - mm) * rs * g4.w + bb4.w + xr[3] + e4.w;
      *(float4*)&g0[base + (size_t)n * TILE + oc] = hv;
    }
    __syncthreads();
  }
}

// ================================================================ megadec (unchanged):
__global__ __launch_bounds__(256, 2) void k_megadec(
    const float* g0, const float* dxcT, const float* dxcb,
    const float* decT, const float* decb, const float* dc1T, const float* dc1b,
    const float* dp2w, const float* dp2b, const int* flag, void* outv) {
  int bn = blockIdx.x, b = bn >> 8, n = bn & 255;
  int f32o = flag[0];
  __shared__ float hs[128 * 68];
  __shared__ float ecs[128 * 68];
  __shared__ float p0[256], p1[256];
  int tid = threadIdx.x;
  const float* gp = g0 + (size_t)bn * TILE;
  for (int idx = tid * 4; idx < TILE; idx += 1024) {
    int t = idx >> 7, c = idx & 127;
    float4 v4 = *(const float4*)&gp[idx];
    hs[(c + 0) * 68 + t + 1] = v4.x;
    hs[(c + 1) * 68 + t + 1] = v4.y;
    hs[(c + 2) * 68 + t + 1] = v4.z;
    hs[(c + 3) * 68 + t + 1] = v4.w;
  }
  if (tid < 128) {
    hs[tid * 68] = 0.f; hs[tid * 68 + 65] = 0.f;
    ecs[tid * 68] = 0.f; ecs[tid * 68 + 65] = 0.f;
  }
  __syncthreads();
  int cg = tid & 31, tc = tid >> 5;
  int o0 = cg * 4, t0 = tc * 8;
  {
    float4 bi = *(const float4*)&decb[o0];
    float acc[8][4];
#pragma unroll
    for (int t = 0; t < 8; ++t) { acc[t][0] = bi.x; acc[t][1] = bi.y; acc[t][2] = bi.z; acc[t][3] = bi.w; }
    for (int i = 0; i < 128; ++i) {
      const float* xr = &hs[i * 68 + t0];
      float xv[10];
#pragma unroll
      for (int u = 0; u < 10; ++u) xv[u] = xr[u];
#pragma unroll
      for (int j = 0; j < 3; ++j) {
        float4 w4 = *(const float4*)&decT[(j * 128 + i) * 128 + o0];
#pragma unroll
        for (int t = 0; t < 8; ++t) {
          float xvv = xv[t + j];
          acc[t][0] += xvv * w4.x; acc[t][1] += xvv * w4.y;
          acc[t][2] += xvv * w4.z; acc[t][3] += xvv * w4.w;
        }
      }
    }
#pragma unroll
    for (int t = 0; t < 8; ++t)
#pragma unroll
      for (int z = 0; z < 4; ++z) ecs[(o0 + z) * 68 + (t0 + t) + 1] = acc[t][z];
  }
  __syncthreads();
  float accx[8][4], accc[8][4];
  {
    float4 bx = *(const float4*)&dxcb[o0];
    float4 bc = *(const float4*)&dc1b[o0];
#pragma unroll
    for (int t = 0; t < 8; ++t) {
      accx[t][0] = bx.x; accx[t][1] = bx.y; accx[t][2] = bx.z; accx[t][3] = bx.w;
      accc[t][0] = bc.x; accc[t][1] = bc.y; accc[t][2] = bc.z; accc[t][3] = bc.w;
    }
    for (int i = 0; i < 128; ++i) {
      const float* hr = &hs[i * 68 + t0];
      const float* er = &ecs[i * 68 + t0];
      float xvh[10], xvc[10];
#pragma unroll
      for (int u = 0; u < 10; ++u) { xvh[u] = hr[u]; xvc[u] = er[u]; }
#pragma unroll
      for (int j = 0; j < 3; ++j) {
        float4 wx = *(const float4*)&dxcT[(j * 128 + i) * 128 + o0];
        float4 wc = *(const float4*)&dc1T[(j * 128 + i) * 128 + o0];
#pragma unroll
        for (int t = 0; t < 8; ++t) {
          float hv = xvh[t + j], ev = xvc[t + j];
          accx[t][0] += hv * wx.x; accx[t][1] += hv * wx.y;
          accx[t][2] += hv * wx.z; accx[t][3] += hv * wx.w;
          accc[t][0] += ev * wc.x; accc[t][1] += ev * wc.y;
          accc[t][2] += ev * wc.z; accc[t][3] += ev * wc.w;
        }
      }
    }
#pragma unroll
    for (int t = 0; t < 8; ++t) {
      int row = t0 + t;
#pragma unroll
      for (int z = 0; z < 4; ++z) {
        float ecv = ecs[(o0 + z) * 68 + row + 1];
        accx[t][z] = fmaxf(accx[t][z] + sigm(ecv) + accc[t][z], 0.f);
      }
    }
  }
  __syncthreads();
#pragma unroll
  for (int t = 0; t < 8; ++t)
#pragma unroll
    for (int z = 0; z < 4; ++z) hs[(o0 + z) * 68 + (t0 + t)] = accx[t][z];
  __syncthreads();
  int tt = tid >> 2, sg4 = tid & 3;
  float a0 = 0.f, a1 = 0.f;
  for (int u = 0; u < 32; ++u) {
    int c = sg4 * 32 + u;
    float v = hs[c * 68 + tt];
    a0 += v * dp2w[c];
    a1 += v * dp2w[128 + c];
  }
  p0[tid] = a0; p1[tid] = a1;
  __syncthreads();
  if (sg4 == 0) {
    float o0v = p0[tid] + p0[tid + 1] + p0[tid + 2] + p0[tid + 3] + dp2b[0];
    float o1v = p1[tid] + p1[tid + 1] + p1[tid + 2] + p1[tid + 3] + dp2b[1];
    size_t i0 = ((size_t)(b * 2 + 0) * 256 + n) * 64 + tt;
    size_t i1 = ((size_t)(b * 2 + 1) * 256 + n) * 64 + tt;
    if (f32o) {
      ((float*)outv)[i0] = o0v;
      ((float*)outv)[i1] = o1v;
    } else {
      ((__hip_bfloat16*)outv)[i0] = __float2bfloat16(o0v);
      ((__hip_bfloat16*)outv)[i1] = __float2bfloat16(o1v);
    }
  }
}

}  // namespace

extern "C" void kernel_launch(void* const* d_in, const int* in_sizes, int n_in,
                              void* d_out, int out_size, void* d_ws, size_t ws_size,
                              hipStream_t stream) {
  (void)in_sizes; (void)n_in; (void)out_size; (void)ws_size;
  const void* x    = d_in[0];
  const void* adj  = d_in[1];
  const int*  step = (const int*)d_in[2];
  const void* wq   = d_in[3];
  const void* bq   = d_in[4];
  const void* wk   = d_in[5];
  const void* bk   = d_in[6];
  const void* w1   = d_in[7];
  const void* b1   = d_in[8];
  const void* w2   = d_in[9];
  const void* b2   = d_in[10];
  const void* th   = d_in[11];
  const void* l0g  = d_in[12];
  const void* l0b  = d_in[13];
  const void* l1g  = d_in[14];
  const void* l1b  = d_in[15];
  const void* p1w  = d_in[16];
  const void* p1b  = d_in[17];
  const void* p2w  = d_in[18];
  const void* p2b  = d_in[19];
  const void* dxcw = d_in[20];
  const void* dxcb = d_in[21];
  const void* decw = d_in[22];
  const void* decb = d_in[23];
  const void* dc1w = d_in[24];
  const void* dc1b = d_in[25];
  const void* dp2w = d_in[26];
  const void* dp2b = d_in[27];

  float* ws = (float*)d_ws;
  int* flag = (int*)ws;
  float* p = ws + 16;
  float* e     = p; p += 1024;
  float* lap   = p; p += 65536;
  float* wqkT  = p; p += 98304;
  float* w1T   = p; p += 16384;
  float* w2T   = p; p += 16384;
  float* thT   = p; p += 16384;
  float* dxcT  = p; p += 49152;
  float* decT  = p; p += 49152;
  float* dc1T  = p; p += 49152;
  float* bqk   = p; p += 256;
  float* b1f   = p; p += 128;
  float* b2f   = p; p += 128;
  float* l0gf  = p; p += 128;
  float* l0bf  = p; p += 128;
  float* l1gf  = p; p += 128;
  float* l1bf  = p; p += 128;
  float* dxcbf = p; p += 128;
  float* decbf = p; p += 128;
  float* dc1bf = p; p += 128;
  float* dp2wf = p; p += 256;
  float* dp2bf = p; p += 8;
  size_t off = (size_t)(p - ws);
  off = (off + 127) & ~(size_t)127;
  float* xf = ws + off;            // BIGE floats (67 MB)
  float* g0 = xf + BIGE;           // BIGE floats (67 MB)

  PrepArgs pa;
  pa.flag = flag;
  pa.wq = wq; pa.wk = wk; pa.w1 = w1; pa.w2 = w2; pa.th = th;
  pa.dxc = dxcw; pa.dec = decw; pa.dc1 = dc1w;
  pa.bq = bq; pa.bk = bk; pa.b1 = b1; pa.b2 = b2;
  pa.l0g = l0g; pa.l0b = l0b; pa.l1g = l1g; pa.l1b = l1b;
  pa.dxcb = dxcb; pa.decb = decb; pa.dc1b = dc1b; pa.dp2w = dp2w; pa.dp2b = dp2b;
  pa.wqkT = wqkT; pa.w1T = w1T; pa.w2T = w2T; pa.thT = thT;
  pa.dxcT = dxcT; pa.decT = decT; pa.dc1T = dc1T;
  pa.bqk = bqk; pa.b1f = b1f; pa.b2f = b2f;
  pa.l0gf = l0gf; pa.l0bf = l0bf; pa.l1gf = l1gf; pa.l1bf = l1bf;
  pa.dxcbf = dxcbf; pa.decbf = decbf; pa.dc1bf = dc1bf; pa.dp2wf = dp2wf; pa.dp2bf = dp2bf;

  k_sniff<<<1, 64, 0, stream>>>((const unsigned short*)x, flag);
  k_cvtx<<<1024, 256, 0, stream>>>(x, flag, xf);
  k_prep<<<128, 256, 0, stream>>>(pa);
  k_lap<<<1, 256, 0, stream>>>(adj, flag, lap);
  k_emb<<<8, 128, 0, stream>>>(step, flag, p1w, p1b, p2w, p2b, e);

  k_mega1<<<2048, 256, 0, stream>>>(xf, wqkT, bqk, w1T, b1f, w2T, b2f, l0gf, l0bf, g0);
  k_megasp<<<512, 512, 0, stream>>>(g0, lap, thT, l1gf, l1bf, e);
  k_megadec<<<2048, 256, 0, stream>>>(g0, dxcT, dxcbf, decT, decbf, dc1T, dc1bf,
                                      dp2wf, dp2bf, flag, d_out);
}

// Round 5
// 2048.551 us; speedup vs baseline: 1.2697x; 1.0228x over previous
//
#include <hip/hip_runtime.h>
#include <hip/hip_bf16.h>

namespace {

constexpr int C = 128, N = 256, T = 64, Bsz = 8;
constexpr int TILE = T * C;                       // 8192 elements per (b,n) slab
constexpr size_t BIGE = (size_t)Bsz * N * T * C;  // 16,777,216 elements

__device__ __forceinline__ float bfu(unsigned short u) {
  unsigned int x = ((unsigned int)u) << 16;
  return __uint_as_float(x);
}
// flag-aware load: f32 != 0 -> input is fp32, else bf16
__device__ __forceinline__ float ld(const void* p, size_t i, int f32) {
  if (f32) return ((const float*)p)[i];
  return bfu(((const unsigned short*)p)[i]);
}
__device__ __forceinline__ float sigm(float x) { return 1.f / (1.f + __expf(-x)); }

// ---------------------------------------------------------------- dtype sniffer
__global__ __launch_bounds__(64) void k_sniff(const unsigned short* x, int* flag) {
  __shared__ int cnt[64];
  int tid = threadIdx.x;
  int c = 0;
  for (int u = 0; u < 8; ++u) {
    unsigned short v = x[tid * 8 + u];
    int e = (v >> 7) & 255;
    c += (e >= 97 && e <= 157) ? 1 : 0;
  }
  cnt[tid] = c;
  __syncthreads();
  if (tid == 0) {
    int s = 0;
    for (int i = 0; i < 64; ++i) s += cnt[i];
    flag[0] = (s < 435) ? 1 : 0;  // <85% plausible-bf16 words -> fp32 input
  }
}

// ---------------------------------------------------------------- x -> fp32 copy
__global__ __launch_bounds__(256) void k_cvtx(const void* x, const int* flag, float* xf) {
  int f = flag[0];
  size_t i0 = ((size_t)blockIdx.x * 256 + threadIdx.x) * 4;
  size_t stride = (size_t)gridDim.x * 1024;
  if (f) {
    const float4* src = (const float4*)x;
    for (size_t i = i0; i < BIGE; i += stride) *(float4*)&xf[i] = src[i >> 2];
  } else {
    const ushort4* src = (const ushort4*)x;
    for (size_t i = i0; i < BIGE; i += stride) {
      ushort4 u = src[i >> 2];
      float4 v; v.x = bfu(u.x); v.y = bfu(u.y); v.z = bfu(u.z); v.w = bfu(u.w);
      *(float4*)&xf[i] = v;
    }
  }
}

// ---------------------------------------------------------------- prep (weights -> fp32, k-major)
struct PrepArgs {
  const int* flag;
  const void *wq, *wk, *w1, *w2, *th, *dxc, *dec, *dc1;
  const void *bq, *bk, *b1, *b2, *l0g, *l0b, *l1g, *l1b, *dxcb, *decb, *dc1b, *dp2w, *dp2b;
  float *wqkT, *w1T, *w2T, *thT, *dxcT, *decT, *dc1T;
  float *bqk, *b1f, *b2f, *l0gf, *l0bf, *l1gf, *l1bf, *dxcbf, *decbf, *dc1bf, *dp2wf, *dp2bf;
};

__global__ __launch_bounds__(256) void k_prep(PrepArgs a) {
  int f = a.flag[0];
  int idx = blockIdx.x * blockDim.x + threadIdx.x;
  int stride = gridDim.x * blockDim.x;
  for (int i = idx; i < 384 * 256; i += stride) {
    int k = i >> 8, o = i & 255, j = k >> 7, ii = k & 127;
    a.wqkT[i] = (o < 128) ? ld(a.wq, (o * 128 + ii) * 3 + j, f)
                          : ld(a.wk, ((o - 128) * 128 + ii) * 3 + j, f);
  }
  for (int i = idx; i < 16384; i += stride) {
    int k = i >> 7, o = i & 127;
    a.w1T[i] = ld(a.w1, o * 128 + k, f);
    a.w2T[i] = ld(a.w2, o * 128 + k, f);
    a.thT[i] = ld(a.th, o * 128 + k, f);
  }
  for (int i = idx; i < 384 * 128; i += stride) {
    int k = i >> 7, o = i & 127, j = k >> 7, ii = k & 127;
    int s = (o * 128 + ii) * 3 + j;
    a.dxcT[i] = ld(a.dxc, s, f); a.decT[i] = ld(a.dec, s, f); a.dc1T[i] = ld(a.dc1, s, f);
  }
  for (int i = idx; i < 256; i += stride) {
    a.bqk[i] = (i < 128) ? ld(a.bq, i, f) : ld(a.bk, i - 128, f);
    a.dp2wf[i] = ld(a.dp2w, i, f);
  }
  for (int i = idx; i < 128; i += stride) {
    a.b1f[i] = ld(a.b1, i, f);   a.b2f[i] = ld(a.b2, i, f);
    a.l0gf[i] = ld(a.l0g, i, f); a.l0bf[i] = ld(a.l0b, i, f);
    a.l1gf[i] = ld(a.l1g, i, f); a.l1bf[i] = ld(a.l1b, i, f);
    a.dxcbf[i] = ld(a.dxcb, i, f); a.decbf[i] = ld(a.decb, i, f); a.dc1bf[i] = ld(a.dc1b, i, f);
  }
  if (idx < 2) a.dp2bf[idx] = ld(a.dp2b, idx, f);
}

__global__ __launch_bounds__(256) void k_lap(const void* adj, const int* flag, float* lap) {
  __shared__ float dsh[256];
  int f = flag[0];
  int tid = threadIdx.x;
  float s = 0.f;
  for (int m = 0; m < 256; ++m) s += ld(adj, tid * 256 + m, f);
  dsh[tid] = 1.f / sqrtf(s);
  __syncthreads();
  for (int idx = tid; idx < 65536; idx += 256) {
    int n = idx >> 8, m = idx & 255;
    lap[idx] = ld(adj, idx, f) * dsh[n] * dsh[m];
  }
}

__global__ __launch_bounds__(128) void k_emb(const int* step, const int* flag,
                                             const void* p1w, const void* p1b,
                                             const void* p2w, const void* p2b, float* e) {
  int b = blockIdx.x, c = threadIdx.x;
  int f = flag[0];
  __shared__ float tab[128], e1[128];
  float sv = (float)step[b];
  int i0 = c & 63;
  float fr = powf(10.f, (float)i0 / 63.f * 4.f);
  float ang = sv * fr;
  tab[c] = (c < 64) ? sinf(ang) : cosf(ang);
  __syncthreads();
  float a = ld(p1b, c, f);
  for (int i = 0; i < 128; ++i) a += tab[i] * ld(p1w, c * 128 + i, f);
  a = a * sigm(a);
  e1[c] = a;
  __syncthreads();
  float a2 = ld(p2b, c, f);
  for (int i = 0; i < 128; ++i) a2 += e1[i] * ld(p2w, c * 128 + i, f);
  e[b * 128 + c] = a2 * sigm(a2);
}

// ================================================================ mega1 v3 (512 threads):
// per (b,n): x -> QK conv GEMM, V GEMM, 8-head temporal attention (register
// softmax, shuffle reductions, zero barriers in head loop), o.w2^T, LN0 +
// residual -> xp (fp32) to g0.
__global__ __launch_bounds__(512, 1) void k_mega1(
    const float* xf, const float* wqkT, const float* bqk,
    const float* w1T, const float* b1f, const float* w2T, const float* b2f,
    const float* l0g, const float* l0b, float* g0) {
  int bn = blockIdx.x, b = bn >> 8, n = bn & 255;
  __shared__ float xs[128 * 68];    // x tile, [c][t+1], zero pads at tt=0,65
  __shared__ float qls[64 * 132];   // q [t][c]; later o [t][c]
  __shared__ float kls[64 * 132];   // k [t][c]; later o.w2^T [t][c]
  __shared__ float vls[64 * 132];   // v [t][c]; later o^T [c*66+t]
  __shared__ float mrow[64], vrow[64];
  int tid = threadIdx.x;
  const float* xb = xf + (size_t)b * C * N * T + (size_t)n * T;
  for (int idx = tid * 4; idx < TILE; idx += 2048) {
    int i = idx >> 6, t = idx & 63;
    float4 v4 = *(const float4*)&xb[(size_t)i * N * T + t];
    float* row = &xs[i * 68 + t + 1];
    row[0] = v4.x; row[1] = v4.y; row[2] = v4.z; row[3] = v4.w;
  }
  if (tid < 128) { xs[tid * 68] = 0.f; xs[tid * 68 + 65] = 0.f; }
  __syncthreads();
  // ---- QK conv GEMM (K=384, 256 cols) -> qls, kls.  8 t x 4 o per thread.
  {
    int cg = tid & 63, tc = tid >> 6;      // tc 0..7
    int o0 = cg * 4, t0 = tc * 8;
    float4 bi = *(const float4*)&bqk[o0];
    float acc[8][4];
#pragma unroll
    for (int t = 0; t < 8; ++t) { acc[t][0] = bi.x; acc[t][1] = bi.y; acc[t][2] = bi.z; acc[t][3] = bi.w; }
    for (int i = 0; i < 128; ++i) {
      const float* xr = &xs[i * 68 + t0];
      float xv[10];
#pragma unroll
      for (int u = 0; u < 10; ++u) xv[u] = xr[u];
#pragma unroll
      for (int j = 0; j < 3; ++j) {
        float4 w4 = *(const float4*)&wqkT[(j * 128 + i) * 256 + o0];
#pragma unroll
        for (int t = 0; t < 8; ++t) {
          float xvv = xv[t + j];
          acc[t][0] += xvv * w4.x; acc[t][1] += xvv * w4.y;
          acc[t][2] += xvv * w4.z; acc[t][3] += xvv * w4.w;
        }
      }
    }
    float* dst = (o0 < 128) ? qls : kls;
    int oo = o0 & 127;
#pragma unroll
    for (int t = 0; t < 8; ++t) {
      float4 r4; r4.x = acc[t][0]; r4.y = acc[t][1]; r4.z = acc[t][2]; r4.w = acc[t][3];
      *(float4*)&dst[(t0 + t) * 132 + oo] = r4;
    }
  }
  // ---- V GEMM (K=128) -> vls.  4 t x 4 o per thread.
  {
    int cg = tid & 31, tc = tid >> 5;      // tc 0..15
    int o0 = cg * 4, t0 = tc * 4;
    float4 bi = *(const float4*)&b1f[o0];
    float acc[4][4];
#pragma unroll
    for (int t = 0; t < 4; ++t) { acc[t][0] = bi.x; acc[t][1] = bi.y; acc[t][2] = bi.z; acc[t][3] = bi.w; }
    for (int i = 0; i < 128; ++i) {
      const float* xr = &xs[i * 68 + t0 + 1];
      float4 w4 = *(const float4*)&w1T[i * 128 + o0];
#pragma unroll
      for (int t = 0; t < 4; ++t) {
        float xv = xr[t];
        acc[t][0] += xv * w4.x; acc[t][1] += xv * w4.y; acc[t][2] += xv * w4.z; acc[t][3] += xv * w4.w;
      }
    }
#pragma unroll
    for (int t = 0; t < 4; ++t) {
      float4 r4; r4.x = acc[t][0]; r4.y = acc[t][1]; r4.z = acc[t][2]; r4.w = acc[t][3];
      *(float4*)&vls[(t0 + t) * 132 + o0] = r4;
    }
  }
  __syncthreads();
  // ---- temporal attention: 8-lane group per q-row t; heads sequential.
  // Each wave owns rows [w*8, w*8+8) exclusively -> no barriers needed.
  {
    int t = tid >> 3;      // 0..63 (q row)
    int sg = tid & 7;      // lane in row-group
    for (int h = 0; h < 8; ++h) {
      int hb = h * 16;
      // load q[t, hb..hb+15] (broadcast within row-group)
      float4 q0 = *(const float4*)&qls[t * 132 + hb];
      float4 q1 = *(const float4*)&qls[t * 132 + hb + 4];
      float4 q2 = *(const float4*)&qls[t * 132 + hb + 8];
      float4 q3 = *(const float4*)&qls[t * 132 + hb + 12];
      float a[8];
#pragma unroll
      for (int j = 0; j < 8; ++j) {
        int s = sg + 8 * j;
        const float* kr = &kls[s * 132 + hb];
        float4 k0 = *(const float4*)&kr[0];
        float4 k1 = *(const float4*)&kr[4];
        float4 k2 = *(const float4*)&kr[8];
        float4 k3 = *(const float4*)&kr[12];
        a[j] = (q0.x * k0.x + q0.y * k0.y + q0.z * k0.z + q0.w * k0.w +
                q1.x * k1.x + q1.y * k1.y + q1.z * k1.z + q1.w * k1.w +
                q2.x * k2.x + q2.y * k2.y + q2.z * k2.z + q2.w * k2.w +
                q3.x * k3.x + q3.y * k3.y + q3.z * k3.z + q3.w * k3.w) * 0.25f;
      }
      float mx = a[0];
#pragma unroll
      for (int j = 1; j < 8; ++j) mx = fmaxf(mx, a[j]);
#pragma unroll
      for (int m = 4; m > 0; m >>= 1) mx = fmaxf(mx, __shfl_xor(mx, m, 8));
      float sum = 0.f;
#pragma unroll
      for (int j = 0; j < 8; ++j) { a[j] = __expf(a[j] - mx); sum += a[j]; }
#pragma unroll
      for (int m = 4; m > 0; m >>= 1) sum += __shfl_xor(sum, m, 8);
      float inv = 1.f / sum;
#pragma unroll
      for (int j = 0; j < 8; ++j) a[j] *= inv;
      // PV: partial o over this thread's 8 s-positions
      float o[16];
#pragma unroll
      for (int d = 0; d < 16; ++d) o[d] = 0.f;
#pragma unroll
      for (int j = 0; j < 8; ++j) {
        int s = sg + 8 * j;
        const float* vr = &vls[s * 132 + hb];
        float w = a[j];
#pragma unroll
        for (int d = 0; d < 16; ++d) o[d] += w * vr[d];
      }
      // butterfly-reduce o across the 8-lane row group
#pragma unroll
      for (int m = 4; m > 0; m >>= 1)
#pragma unroll
        for (int d = 0; d < 16; ++d) o[d] += __shfl_xor(o[d], m, 8);
      // lanes 0..3 write one float4 each (all lanes hold full sums)
      if (sg < 4) {
        float4 r4;
        r4.x = o[sg * 4 + 0]; r4.y = o[sg * 4 + 1];
        r4.z = o[sg * 4 + 2]; r4.w = o[sg * 4 + 3];
        *(float4*)&qls[t * 132 + hb + sg * 4] = r4;
      }
    }
  }
  __syncthreads();
  // ---- transpose o -> tr (reuse vls as [c*66 + t])
  float* tr = vls;
  for (int idx = tid; idx < TILE; idx += 512) {
    int t = idx >> 7, c = idx & 127;
    tr[c * 66 + t] = qls[t * 132 + c];
  }
  __syncthreads();
  // ---- w2 GEMM: ls[t][o] = sum_i o[t][i]*w2[o][i] + b2 -> kls. 4 t x 4 o.
  {
    int cg = tid & 31, tc = tid >> 5;
    int o0 = cg * 4, t0 = tc * 4;
    float4 bi = *(const float4*)&b2f[o0];
    float acc[4][4];
#pragma unroll
    for (int t = 0; t < 4; ++t) { acc[t][0] = bi.x; acc[t][1] = bi.y; acc[t][2] = bi.z; acc[t][3] = bi.w; }
    for (int i = 0; i < 128; ++i) {
      const float* xr = &tr[i * 66 + t0];
      float4 w4 = *(const float4*)&w2T[i * 128 + o0];
#pragma unroll
      for (int t = 0; t < 4; ++t) {
        float xv = xr[t];
        acc[t][0] += xv * w4.x; acc[t][1] += xv * w4.y; acc[t][2] += xv * w4.z; acc[t][3] += xv * w4.w;
      }
    }
#pragma unroll
    for (int t = 0; t < 4; ++t) {
      float4 r4; r4.x = acc[t][0]; r4.y = acc[t][1]; r4.z = acc[t][2]; r4.w = acc[t][3];
      *(float4*)&kls[(t0 + t) * 132 + o0] = r4;
    }
  }
  __syncthreads();
  // ---- LN0 stats via shuffles: 8-lane group per row
  {
    int r = tid >> 3, sg = tid & 7;
    float s = 0.f, q2 = 0.f;
    const float* row = &kls[r * 132 + sg * 16];
    for (int u = 0; u < 16; ++u) {
      float v = row[u];
      s += v; q2 += v * v;
    }
#pragma unroll
    for (int m = 4; m > 0; m >>= 1) {
      s += __shfl_xor(s, m, 8);
      q2 += __shfl_xor(q2, m, 8);
    }
    if (sg == 0) {
      float mm = s * (1.f / 128.f);
      mrow[r] = mm;
      vrow[r] = rsqrtf(q2 * (1.f / 128.f) - mm * mm + 1e-5f);
    }
  }
  __syncthreads();
  float* dst = g0 + (size_t)bn * TILE;
  for (int idx = tid; idx < TILE; idx += 512) {
    int t = idx >> 7, c = idx & 127;
    dst[idx] = (kls[t * 132 + c] - mrow[t]) * vrow[t] * l0g[c] + l0b[c] + xs[c * 68 + t + 1];
  }
}

// ================================================================ megasp v2 (unchanged):
__global__ __launch_bounds__(512, 1) void k_megasp(
    float* g0, const float* lap, const float* thT,
    const float* l1g, const float* l1b, const float* e) {
  int bt = blockIdx.x, b = bt >> 6, t = bt & 63;
  __shared__ float xts[256 * 132];
  __shared__ float scs[16 * 260];
  __shared__ float ybuf[16 * 132];
  int tid = threadIdx.x;
  size_t base = (size_t)b * (N * (size_t)TILE) + (size_t)t * 128;
  for (int idx = tid * 4; idx < 32768; idx += 2048) {
    int n = idx >> 7, c = idx & 127;
    float4 v4 = *(const float4*)&g0[base + (size_t)n * TILE + c];
    *(float4*)&xts[n * 132 + c] = v4;
  }
  __syncthreads();
  const float sc = 0.08838834764831845f;
  const float* eb = e + b * 128;
  int r = tid >> 5;
  int sg = tid & 31;
  int oc = sg * 4;
  float4 g4 = *(const float4*)&l1g[oc];
  float4 bb4 = *(const float4*)&l1b[oc];
  float4 e4 = *(const float4*)&eb[oc];
  for (int chunk = 0; chunk < 16; ++chunk) {
    int n0 = chunk * 16;
    int n = n0 + r;
    float a[8];
#pragma unroll
    for (int jj = 0; jj < 8; ++jj) a[jj] = 0.f;
    const float* qrow = &xts[n * 132];
    for (int k = 0; k < 128; k += 4) {
      float4 q4 = *(const float4*)&qrow[k];
#pragma unroll
      for (int jj = 0; jj < 8; ++jj) {
        const float4 m4 = *(const float4*)&xts[(sg + 32 * jj) * 132 + k];
        a[jj] += q4.x * m4.x + q4.y * m4.y + q4.z * m4.z + q4.w * m4.w;
      }
    }
    float mloc = -1e30f;
#pragma unroll
    for (int jj = 0; jj < 8; ++jj) { a[jj] *= sc; mloc = fmaxf(mloc, a[jj]); }
#pragma unroll
    for (int s = 16; s > 0; s >>= 1) mloc = fmaxf(mloc, __shfl_xor(mloc, s, 32));
    float ssum = 0.f;
#pragma unroll
    for (int jj = 0; jj < 8; ++jj) { a[jj] = __expf(a[jj] - mloc); ssum += a[jj]; }
#pragma unroll
    for (int s = 16; s > 0; s >>= 1) ssum += __shfl_xor(ssum, s, 32);
    float inv = sc / ssum;
    const float* lrow = &lap[n * 256];
#pragma unroll
    for (int jj = 0; jj < 8; ++jj) {
      int m = sg + 32 * jj;
      scs[r * 260 + m] = a[jj] * inv * lrow[m];
    }
    __syncthreads();
    {
      float4 acc = {0.f, 0.f, 0.f, 0.f};
      const float* srow = &scs[r * 260];
      for (int m2 = 0; m2 < 256; ++m2) {
        float w = srow[m2];
        float4 x4 = *(const float4*)&xts[m2 * 132 + oc];
        acc.x += w * x4.x; acc.y += w * x4.y; acc.z += w * x4.z; acc.w += w * x4.w;
      }
      *(float4*)&ybuf[r * 132 + oc] = acc;
    }
    __syncthreads();
    {
      float4 acc = {0.f, 0.f, 0.f, 0.f};
      const float* yrow = &ybuf[r * 132];
      for (int i = 0; i < 128; ++i) {
        float yv = yrow[i];
        float4 w4 = *(const float4*)&thT[i * 128 + oc];
        acc.x += yv * w4.x; acc.y += yv * w4.y; acc.z += yv * w4.z; acc.w += yv * w4.w;
      }
      acc.x = fmaxf(acc.x, 0.f); acc.y = fmaxf(acc.y, 0.f);
      acc.z = fmaxf(acc.z, 0.f); acc.w = fmaxf(acc.w, 0.f);
      float sps = acc.x + acc.y + acc.z + acc.w;
      float spq = acc.x * acc.x + acc.y * acc.y + acc.z * acc.z + acc.w * acc.w;
#pragma unroll
      for (int s = 16; s > 0; s >>= 1) {
        sps += __shfl_xor(sps, s, 32);
        spq += __shfl_xor(spq, s, 32);
      }
      float mm = sps * (1.f / 128.f);
      float rs = rsqrtf(spq * (1.f / 128.f) - mm * mm + 1e-5f);
      const float* xr = &xts[n * 132 + oc];
      float4 hv;
      hv.x = (acc.x - mm) * rs * g4.x + bb4.x + xr[0] + e4.x;
      hv.y = (acc.y - mm) * rs * g4.y + bb4.y + xr[1] + e4.y;
      hv.z = (acc.z - mm) * rs * g4.z + bb4.z + xr[2] + e4.z;
      hv.w = (acc.w - mm) * rs * g4.w + bb4.w + xr[3] + e4.w;
      *(float4*)&g0[base + (size_t)n * TILE + oc] = hv;
    }
    __syncthreads();
  }
}

// ================================================================ megadec (unchanged):
__global__ __launch_bounds__(256, 2) void k_megadec(
    const float* g0, const float* dxcT, const float* dxcb,
    const float* decT, const float* decb, const float* dc1T, const float* dc1b,
    const float* dp2w, const float* dp2b, const int* flag, void* outv) {
  int bn = blockIdx.x, b = bn >> 8, n = bn & 255;
  int f32o = flag[0];
  __shared__ float hs[128 * 68];
  __shared__ float ecs[128 * 68];
  __shared__ float p0[256], p1[256];
  int tid = threadIdx.x;
  const float* gp = g0 + (size_t)bn * TILE;
  for (int idx = tid * 4; idx < TILE; idx += 1024) {
    int t = idx >> 7, c = idx & 127;
    float4 v4 = *(const float4*)&gp[idx];
    hs[(c + 0) * 68 + t + 1] = v4.x;
    hs[(c + 1) * 68 + t + 1] = v4.y;
    hs[(c + 2) * 68 + t + 1] = v4.z;
    hs[(c + 3) * 68 + t + 1] = v4.w;
  }
  if (tid < 128) {
    hs[tid * 68] = 0.f; hs[tid * 68 + 65] = 0.f;
    ecs[tid * 68] = 0.f; ecs[tid * 68 + 65] = 0.f;
  }
  __syncthreads();
  int cg = tid & 31, tc = tid >> 5;
  int o0 = cg * 4, t0 = tc * 8;
  {
    float4 bi = *(const float4*)&decb[o0];
    float acc[8][4];
#pragma unroll
    for (int t = 0; t < 8; ++t) { acc[t][0] = bi.x; acc[t][1] = bi.y; acc[t][2] = bi.z; acc[t][3] = bi.w; }
    for (int i = 0; i < 128; ++i) {
      const float* xr = &hs[i * 68 + t0];
      float xv[10];
#pragma unroll
      for (int u = 0; u < 10; ++u) xv[u] = xr[u];
#pragma unroll
      for (int j = 0; j < 3; ++j) {
        float4 w4 = *(const float4*)&decT[(j * 128 + i) * 128 + o0];
#pragma unroll
        for (int t = 0; t < 8; ++t) {
          float xvv = xv[t + j];
          acc[t][0] += xvv * w4.x; acc[t][1] += xvv * w4.y;
          acc[t][2] += xvv * w4.z; acc[t][3] += xvv * w4.w;
        }
      }
    }
#pragma unroll
    for (int t = 0; t < 8; ++t)
#pragma unroll
      for (int z = 0; z < 4; ++z) ecs[(o0 + z) * 68 + (t0 + t) + 1] = acc[t][z];
  }
  __syncthreads();
  float accx[8][4], accc[8][4];
  {
    float4 bx = *(const float4*)&dxcb[o0];
    float4 bc = *(const float4*)&dc1b[o0];
#pragma unroll
    for (int t = 0; t < 8; ++t) {
      accx[t][0] = bx.x; accx[t][1] = bx.y; accx[t][2] = bx.z; accx[t][3] = bx.w;
      accc[t][0] = bc.x; accc[t][1] = bc.y; accc[t][2] = bc.z; accc[t][3] = bc.w;
    }
    for (int i = 0; i < 128; ++i) {
      const float* hr = &hs[i * 68 + t0];
      const float* er = &ecs[i * 68 + t0];
      float xvh[10], xvc[10];
#pragma unroll
      for (int u = 0; u < 10; ++u) { xvh[u] = hr[u]; xvc[u] = er[u]; }
#pragma unroll
      for (int j = 0; j < 3; ++j) {
        float4 wx = *(const float4*)&dxcT[(j * 128 + i) * 128 + o0];
        float4 wc = *(const float4*)&dc1T[(j * 128 + i) * 128 + o0];
#pragma unroll
        for (int t = 0; t < 8; ++t) {
          float hv = xvh[t + j], ev = xvc[t + j];
          accx[t][0] += hv * wx.x; accx[t][1] += hv * wx.y;
          accx[t][2] += hv * wx.z; accx[t][3] += hv * wx.w;
          accc[t][0] += ev * wc.x; accc[t][1] += ev * wc.y;
          accc[t][2] += ev * wc.z; accc[t][3] += ev * wc.w;
        }
      }
    }
#pragma unroll
    for (int t = 0; t < 8; ++t) {
      int row = t0 + t;
#pragma unroll
      for (int z = 0; z < 4; ++z) {
        float ecv = ecs[(o0 + z) * 68 + row + 1];
        accx[t][z] = fmaxf(accx[t][z] + sigm(ecv) + accc[t][z], 0.f);
      }
    }
  }
  __syncthreads();
#pragma unroll
  for (int t = 0; t < 8; ++t)
#pragma unroll
    for (int z = 0; z < 4; ++z) hs[(o0 + z) * 68 + (t0 + t)] = accx[t][z];
  __syncthreads();
  int tt = tid >> 2, sg4 = tid & 3;
  float a0 = 0.f, a1 = 0.f;
  for (int u = 0; u < 32; ++u) {
    int c = sg4 * 32 + u;
    float v = hs[c * 68 + tt];
    a0 += v * dp2w[c];
    a1 += v * dp2w[128 + c];
  }
  p0[tid] = a0; p1[tid] = a1;
  __syncthreads();
  if (sg4 == 0) {
    float o0v = p0[tid] + p0[tid + 1] + p0[tid + 2] + p0[tid + 3] + dp2b[0];
    float o1v = p1[tid] + p1[tid + 1] + p1[tid + 2] + p1[tid + 3] + dp2b[1];
    size_t i0 = ((size_t)(b * 2 + 0) * 256 + n) * 64 + tt;
    size_t i1 = ((size_t)(b * 2 + 1) * 256 + n) * 64 + tt;
    if (f32o) {
      ((float*)outv)[i0] = o0v;
      ((float*)outv)[i1] = o1v;
    } else {
      ((__hip_bfloat16*)outv)[i0] = __float2bfloat16(o0v);
      ((__hip_bfloat16*)outv)[i1] = __float2bfloat16(o1v);
    }
  }
}

}  // namespace

extern "C" void kernel_launch(void* const* d_in, const int* in_sizes, int n_in,
                              void* d_out, int out_size, void* d_ws, size_t ws_size,
                              hipStream_t stream) {
  (void)in_sizes; (void)n_in; (void)out_size; (void)ws_size;
  const void* x    = d_in[0];
  const void* adj  = d_in[1];
  const int*  step = (const int*)d_in[2];
  const void* wq   = d_in[3];
  const void* bq   = d_in[4];
  const void* wk   = d_in[5];
  const void* bk   = d_in[6];
  const void* w1   = d_in[7];
  const void* b1   = d_in[8];
  const void* w2   = d_in[9];
  const void* b2   = d_in[10];
  const void* th   = d_in[11];
  const void* l0g  = d_in[12];
  const void* l0b  = d_in[13];
  const void* l1g  = d_in[14];
  const void* l1b  = d_in[15];
  const void* p1w  = d_in[16];
  const void* p1b  = d_in[17];
  const void* p2w  = d_in[18];
  const void* p2b  = d_in[19];
  const void* dxcw = d_in[20];
  const void* dxcb = d_in[21];
  const void* decw = d_in[22];
  const void* decb = d_in[23];
  const void* dc1w = d_in[24];
  const void* dc1b = d_in[25];
  const void* dp2w = d_in[26];
  const void* dp2b = d_in[27];

  float* ws = (float*)d_ws;
  int* flag = (int*)ws;
  float* p = ws + 16;
  float* e     = p; p += 1024;
  float* lap   = p; p += 65536;
  float* wqkT  = p; p += 98304;
  float* w1T   = p; p += 16384;
  float* w2T   = p; p += 16384;
  float* thT   = p; p += 16384;
  float* dxcT  = p; p += 49152;
  float* decT  = p; p += 49152;
  float* dc1T  = p; p += 49152;
  float* bqk   = p; p += 256;
  float* b1f   = p; p += 128;
  float* b2f   = p; p += 128;
  float* l0gf  = p; p += 128;
  float* l0bf  = p; p += 128;
  float* l1gf  = p; p += 128;
  float* l1bf  = p; p += 128;
  float* dxcbf = p; p += 128;
  float* decbf = p; p += 128;
  float* dc1bf = p; p += 128;
  float* dp2wf = p; p += 256;
  float* dp2bf = p; p += 8;
  size_t off = (size_t)(p - ws);
  off = (off + 127) & ~(size_t)127;
  float* xf = ws + off;            // BIGE floats (67 MB)
  float* g0 = xf + BIGE;           // BIGE floats (67 MB)

  PrepArgs pa;
  pa.flag = flag;
  pa.wq = wq; pa.wk = wk; pa.w1 = w1; pa.w2 = w2; pa.th = th;
  pa.dxc = dxcw; pa.dec = decw; pa.dc1 = dc1w;
  pa.bq = bq; pa.bk = bk; pa.b1 = b1; pa.b2 = b2;
  pa.l0g = l0g; pa.l0b = l0b; pa.l1g = l1g; pa.l1b = l1b;
  pa.dxcb = dxcb; pa.decb = decb; pa.dc1b = dc1b; pa.dp2w = dp2w; pa.dp2b = dp2b;
  pa.wqkT = wqkT; pa.w1T = w1T; pa.w2T = w2T; pa.thT = thT;
  pa.dxcT = dxcT; pa.decT = decT; pa.dc1T = dc1T;
  pa.bqk = bqk; pa.b1f = b1f; pa.b2f = b2f;
  pa.l0gf = l0gf; pa.l0bf = l0bf; pa.l1gf = l1gf; pa.l1bf = l1bf;
  pa.dxcbf = dxcbf; pa.decbf = decbf; pa.dc1bf = dc1bf; pa.dp2wf = dp2wf; pa.dp2bf = dp2bf;

  k_sniff<<<1, 64, 0, stream>>>((const unsigned short*)x, flag);
  k_cvtx<<<1024, 256, 0, stream>>>(x, flag, xf);
  k_prep<<<128, 256, 0, stream>>>(pa);
  k_lap<<<1, 256, 0, stream>>>(adj, flag, lap);
  k_emb<<<8, 128, 0, stream>>>(step, flag, p1w, p1b, p2w, p2b, e);

  k_mega1<<<2048, 512, 0, stream>>>(xf, wqkT, bqk, w1T, b1f, w2T, b2f, l0gf, l0bf, g0);
  k_megasp<<<512, 512, 0, stream>>>(g0, lap, thT, l1gf, l1bf, e);
  k_megadec<<<2048, 256, 0, stream>>>(g0, dxcT, dxcbf, decT, decbf, dc1T, dc1bf,
                                      dp2wf, dp2bf, flag, d_out);
}